// Round 7
// baseline (848.439 us; speedup 1.0000x reference)
//
#include <hip/hip_runtime.h>
#include <stdint.h>

// ---------------------------------------------------------------------------
// ResidueGraphModel: aanet_proj (512->1024->1024->512->80, ReLU) -> in_net
// (80->512) -> GIN sum-aggregation + MLP (512->512->512) -> out_net (512->80).
// bf16 MFMA GEMMs (fp32 accumulate), 128x128 tiles, BK=64, 16x16x32 MFMA.
// R7: revert R6 (CSR mega-kernel collapsed count/scatter parallelism 3125->49
// blocks = +19us; 64-row skinny tiles doubled B staging). Back to R5 structure.
// New: (a) the 3 scan dispatches (already 49-block-shaped) merged into ONE
// cooperative kernel - no parallelism lost; (b) L2 split into two row-halves
// (~70us each) so top-5 rocprof stops being 5 replays of one 140us dispatch
// and reveals the mid-tier dispatch costs for the next round.
// GEMM core: XOR-swizzled LDS (0 bank conflicts), operand-swapped MFMA
// (packed 8B C stores), XCD-grouped decode, row-padded A (no clamp),
// aggregation before in_net (80-dim gather, deg-scaled bias in L5).
// Outputs fp32: d_out = [peptide_mask (N*80) | peptide_feat (N*80)].
// ---------------------------------------------------------------------------

using bf16x8 = __attribute__((ext_vector_type(8))) short;
using f32x4  = __attribute__((ext_vector_type(4))) float;

__device__ inline unsigned short f2bf(float f) {
    union { float f; unsigned u; } v; v.f = f;
    unsigned u = v.u;
    u += 0x7FFFu + ((u >> 16) & 1u);   // RNE
    return (unsigned short)(u >> 16);
}
__device__ inline float bf2f(unsigned u16) {
    return __uint_as_float(u16 << 16);
}

// ------------- merged preprocessing ----------------------------------------
// Block ranges: [0, tEnd) -> weight transpose+convert (32x32 tiles, 256 thr)
//               [tEnd, cEnd) -> feat f32->bf16 convert (1024 elems/block)
//               [cEnd, eEnd) -> edge dst counting (256 edges/block)
struct PreDescs {
    const float* W[8]; unsigned short* Wt[8];
    int K[8], M[8], Kp[8], ntx[8], start[8];
    int tEnd, cEnd, eEnd;
    const float* feat; unsigned short* featb; int nFeat;
    const int* ei; int E; int* cnt;
};

__global__ __launch_bounds__(256) void rg_preprocess(PreDescs d) {
    int b = blockIdx.x;
    int tid = threadIdx.x;
    if (b < d.tEnd) {
        // transpose: W[K][M] f32 -> Wt[Mp][Kp] bf16 (pad with 0)
        __shared__ float t[32][33];
        int di = 0;
#pragma unroll
        for (int i = 1; i < 8; ++i) if (b >= d.start[i]) di = i;
        int local = b - d.start[di];
        int bx = local % d.ntx[di];
        int by = local / d.ntx[di];
        const float* W = d.W[di];
        unsigned short* Wt = d.Wt[di];
        int K = d.K[di], M = d.M[di], Kp = d.Kp[di];
        int mb = bx * 32, kb = by * 32;
        int tx = tid & 31, tg = tid >> 5;   // 8 rows per pass, 4 passes
#pragma unroll
        for (int p = 0; p < 4; ++p) {
            int r = tg + p * 8;             // tile row (k-dir)
            int k = kb + r, m = mb + tx;
            t[r][tx] = (k < K && m < M) ? W[(size_t)k * M + m] : 0.f;
        }
        __syncthreads();
#pragma unroll
        for (int p = 0; p < 4; ++p) {
            int r = tg + p * 8;             // tile row (m-dir)
            int mo = mb + r, ko = kb + tx;
            Wt[(size_t)mo * Kp + ko] = f2bf(t[tx][r]);
        }
    } else if (b < d.cEnd) {
        int i = ((b - d.tEnd) * 256 + tid) * 4;
        if (i + 3 < d.nFeat) {
            float4 v = *(const float4*)(d.feat + i);
            ushort4 o; o.x = f2bf(v.x); o.y = f2bf(v.y); o.z = f2bf(v.z); o.w = f2bf(v.w);
            *(ushort4*)(d.featb + i) = o;
        }
    } else {
        int e = (b - d.cEnd) * 256 + tid;
        if (e < d.E) atomicAdd(&d.cnt[d.ei[d.E + e]], 1);
    }
}

// ---------------- GEMM: C[N,Mp] = act(A[N,Kp] @ Wt[Mp,Kp]^T + bscale*bias) --
// XOR swizzle: LDS chunk q (16B) of a tile row r holds global chunk
// (q&7)^(r&7); staging lane loads the matching global address, fragment
// reads apply the same XOR -> zero measured bank conflicts.
// Operand swap: weights as first MFMA operand -> acc regs hold 4 consecutive
// output columns -> 8B packed stores (32B/row per store instruction).
// A buffers are row-padded: no row clamp on staging loads; pad-row results
// are masked at the store (row < Nrows).
template <bool RELU, bool OUT_BF, bool OUT_F32, bool DEGB, int MT>
__global__ __launch_bounds__(256) void rg_gemm(
    const unsigned short* __restrict__ A, const unsigned short* __restrict__ Bt,
    const float* __restrict__ bias, const int* __restrict__ deg, int Mvalid,
    unsigned short* __restrict__ outB, float* __restrict__ outF,
    int Nrows, int Kp, int Mp, int gN)
{
    __shared__ __align__(16) unsigned short As[128 * 64];
    __shared__ __align__(16) unsigned short Bs[128 * 64];

    // XCD-grouped decode: a row strip's MT col-blocks share (bid&7), 8 apart
    // in issue order -> A strip stays hot in L2/L3 across column passes.
    int bid = blockIdx.x;
    int xcd = bid & 7;
    int slot = bid >> 3;
    int c = slot % MT;
    int rsub = slot / MT;
    int rt = rsub * 8 + xcd;
    if (rt >= gN) return;
    const int rowBase = rt * 128;
    const int nBase   = c * 128;

    const int tid  = threadIdx.x;
    const int lane = tid & 63;
    const int w    = tid >> 6;
    const int wm   = w & 1, wn = w >> 1;

    f32x4 acc[4][4];
#pragma unroll
    for (int i = 0; i < 4; ++i)
#pragma unroll
        for (int j = 0; j < 4; ++j) acc[i][j] = (f32x4){0.f, 0.f, 0.f, 0.f};

    const int nkt = Kp >> 6;
    for (int kt = 0; kt < nkt; ++kt) {
        __syncthreads();
        const int k0 = kt * 64;
#pragma unroll
        for (int i = 0; i < 4; ++i) {
            int q   = i * 256 + tid;       // LDS 16B-chunk slot
            int r   = q >> 3;
            int cbg = (q & 7) ^ (r & 7);   // global chunk staged into slot q
            const unsigned short* gp = A + (size_t)(rowBase + r) * Kp + k0 + cbg * 8;
            __builtin_amdgcn_global_load_lds(
                (const __attribute__((address_space(1))) void*)gp,
                (__attribute__((address_space(3))) void*)(&As[q * 8]), 16, 0, 0);
        }
#pragma unroll
        for (int i = 0; i < 4; ++i) {
            int q   = i * 256 + tid;
            int r   = q >> 3;
            int cbg = (q & 7) ^ (r & 7);
            const unsigned short* gp = Bt + (size_t)(nBase + r) * Kp + k0 + cbg * 8;
            __builtin_amdgcn_global_load_lds(
                (const __attribute__((address_space(1))) void*)gp,
                (__attribute__((address_space(3))) void*)(&Bs[q * 8]), 16, 0, 0);
        }
        __syncthreads();
#pragma unroll
        for (int kk = 0; kk < 2; ++kk) {
            bf16x8 a[4], b[4];
            const int cb = kk * 4 + (lane >> 4);
#pragma unroll
            for (int i = 0; i < 4; ++i) {
                int r = wm * 64 + i * 16 + (lane & 15);
                a[i] = *(const bf16x8*)&As[(r * 8 + (cb ^ (r & 7))) * 8];
            }
#pragma unroll
            for (int j = 0; j < 4; ++j) {
                int r = wn * 64 + j * 16 + (lane & 15);
                b[j] = *(const bf16x8*)&Bs[(r * 8 + (cb ^ (r & 7))) * 8];
            }
#pragma unroll
            for (int i = 0; i < 4; ++i)
#pragma unroll
                for (int j = 0; j < 4; ++j)
                    // swapped: weights first -> D cols from regs, rows from lane
                    acc[i][j] = __builtin_amdgcn_mfma_f32_16x16x32_bf16(b[j], a[i], acc[i][j], 0, 0, 0);
        }
    }

    // epilogue (swapped layout): row = ...+(lane&15); col = ...+quad*4+reg
    const int quad = lane >> 4;
#pragma unroll
    for (int i = 0; i < 4; ++i) {
        int row = rowBase + wm * 64 + i * 16 + (lane & 15);
        if (row >= Nrows) continue;
        float sc = 1.f;
        if (DEGB) sc = 1.f + (float)deg[row];
#pragma unroll
        for (int j = 0; j < 4; ++j) {
            int colb = nBase + wn * 64 + j * 16 + quad * 4;
            float4 bv = (colb < Mvalid) ? *(const float4*)(bias + colb)
                                        : (float4){0.f, 0.f, 0.f, 0.f};
            float v0 = acc[i][j][0] + sc * bv.x;
            float v1 = acc[i][j][1] + sc * bv.y;
            float v2 = acc[i][j][2] + sc * bv.z;
            float v3 = acc[i][j][3] + sc * bv.w;
            if (RELU) {
                v0 = v0 > 0.f ? v0 : 0.f; v1 = v1 > 0.f ? v1 : 0.f;
                v2 = v2 > 0.f ? v2 : 0.f; v3 = v3 > 0.f ? v3 : 0.f;
            }
            if (OUT_BF) {
                ushort4 o; o.x = f2bf(v0); o.y = f2bf(v1); o.z = f2bf(v2); o.w = f2bf(v3);
                *(ushort4*)(outB + (size_t)row * Mp + colb) = o;
            }
            if (OUT_F32) {
                if (colb < Mvalid)
                    *(float4*)(outF + (size_t)row * Mvalid + colb) = (float4){v0, v1, v2, v3};
            }
        }
    }
}

// ---------------- merged scan (3 dispatches -> 1) ---------------------------
// 49 blocks x 1024 threads, co-resident (grid << 256 CUs). The three scan
// stages were already 49-block / 1-wave shaped, so a cooperative merge loses
// no parallelism (unlike R6's full-CSR merge). bar is pre-zeroed by the
// same memset as cnt.
__device__ __forceinline__ void rg_gridbar(int* bar, int nb, int phase) {
    __syncthreads();
    if (threadIdx.x == 0) {
        __threadfence();
        atomicAdd(bar, 1);
        int target = phase * nb;
        while (__hip_atomic_load(bar, __ATOMIC_RELAXED, __HIP_MEMORY_SCOPE_AGENT) < target) {}
        __threadfence();
    }
    __syncthreads();
}

__global__ __launch_bounds__(1024) void rg_scan_all(
    const int* __restrict__ cnt, int* __restrict__ rowptr, int* __restrict__ cursor,
    int* __restrict__ bsums, int* bar, int Nn, int E, int nb)
{
    __shared__ int sd[1024];
    const int tid = threadIdx.x;
    const int bid = blockIdx.x;
    const int i   = bid * 1024 + tid;

    // stage 1: block-local inclusive scan of this block's 1024-chunk
    int v = (i < Nn) ? cnt[i] : 0;
    sd[tid] = v;
    __syncthreads();
    for (int off = 1; off < 1024; off <<= 1) {
        int t = (tid >= off) ? sd[tid - off] : 0;
        __syncthreads();
        sd[tid] += t;
        __syncthreads();
    }
    if (tid == 1023) bsums[bid] = sd[1023];
    rg_gridbar(bar, nb, 1);

    // stage 2: exclusive wave-scan of block sums (block 0, nb <= 64)
    if (bid == 0 && tid < 64) {
        int bv = (tid < nb) ? bsums[tid] : 0;
        int incl = bv;
#pragma unroll
        for (int off = 1; off < 64; off <<= 1) {
            int t = __shfl_up(incl, off, 64);
            if (tid >= off) incl += t;
        }
        if (tid < nb) bsums[tid] = incl - bv;   // exclusive
    }
    rg_gridbar(bar, nb, 2);

    // stage 3: write rowptr + cursor (sd persisted across barriers)
    if (i < Nn) {
        int ex = sd[tid] - v + bsums[bid];
        rowptr[i] = ex; cursor[i] = ex;
    }
    if (i == 0) rowptr[Nn] = E;
}

__global__ void rg_scatter_edges(const int* __restrict__ ei, int E,
                                 int* __restrict__ cursor, int* __restrict__ cols) {
    int e = blockIdx.x * 256 + threadIdx.x;
    if (e < E) {
        int d = ei[E + e];
        int p = atomicAdd(&cursor[d], 1);
        cols[p] = ei[e];
    }
}

// ---------------- 80-dim aggregation: s[i] = pf[i] + sum_{src->i} pf[src] --
// pf is [Npad,128] bf16. One wave per node, 1 uint (2 cols) per lane.
// Edge loop unrolled x8: 8 independent outstanding gathers per iteration.
__global__ __launch_bounds__(256) void rg_agg80(
    const unsigned short* __restrict__ pf, const int* __restrict__ rowptr,
    const int* __restrict__ cols, unsigned short* __restrict__ s, int Nn)
{
    int node = blockIdx.x * 4 + (threadIdx.x >> 6);
    if (node >= Nn) return;
    int lane = threadIdx.x & 63;
    const unsigned* xp = (const unsigned*)pf;   // 64 uints per row
    size_t off = (size_t)node * 64 + lane;
    unsigned u = xp[off];
    float a0 = bf2f(u & 0xffffu), a1 = bf2f(u >> 16);
    int beg = rowptr[node], end = rowptr[node + 1];
    int e = beg;
    for (; e + 8 <= end; e += 8) {
        unsigned v[8];
#pragma unroll
        for (int t = 0; t < 8; ++t) v[t] = xp[(size_t)cols[e + t] * 64 + lane];
#pragma unroll
        for (int t = 0; t < 8; ++t) { a0 += bf2f(v[t] & 0xffffu); a1 += bf2f(v[t] >> 16); }
    }
    for (; e < end; ++e) {
        unsigned v = xp[(size_t)cols[e] * 64 + lane];
        a0 += bf2f(v & 0xffffu); a1 += bf2f(v >> 16);
    }
    unsigned o = (unsigned)f2bf(a0) | ((unsigned)f2bf(a1) << 16);
    ((unsigned*)s)[off] = o;
}

// ---------------------------------------------------------------------------
extern "C" void kernel_launch(void* const* d_in, const int* in_sizes, int n_in,
                              void* d_out, int out_size, void* d_ws, size_t ws_size,
                              hipStream_t stream)
{
    const float* feat = (const float*)d_in[0];
    const int*   ei   = (const int*)d_in[1];
    const float* W1 = (const float*)d_in[2];  const float* b1 = (const float*)d_in[3];
    const float* W2 = (const float*)d_in[4];  const float* b2 = (const float*)d_in[5];
    const float* W3 = (const float*)d_in[6];  const float* b3 = (const float*)d_in[7];
    const float* W4 = (const float*)d_in[8];  const float* b4 = (const float*)d_in[9];
    const float* Wi = (const float*)d_in[10]; const float* bi = (const float*)d_in[11];
    const float* Wg1 = (const float*)d_in[12]; const float* bg1 = (const float*)d_in[13];
    const float* Wg2 = (const float*)d_in[14]; const float* bg2 = (const float*)d_in[15];
    const float* Wo = (const float*)d_in[16]; const float* bo = (const float*)d_in[17];

    const int N = in_sizes[0] / 512;   // 50000
    const int E = in_sizes[1] / 2;     // 800000
    const int gN = (N + 127) / 128;    // 391
    const int Npad = gN * 128;         // 50048: GEMM A-loads never clamp

    char* ws = (char*)d_ws;
    size_t o = 0;
    auto alloc = [&](size_t bytes) { char* p = ws + o; o += (bytes + 255) & ~(size_t)255; return p; };
    unsigned short* bufA = (unsigned short*)alloc((size_t)Npad * 1024 * 2); // h1 / pf / g
    unsigned short* bufB = (unsigned short*)alloc((size_t)Npad * 1024 * 2); // h2 / r1
    unsigned short* bufC = (unsigned short*)alloc((size_t)Npad * 512 * 2);  // A0 / h3 / s / g2
    unsigned short* W1t = (unsigned short*)alloc((size_t)1024 * 512 * 2);
    unsigned short* W2t = (unsigned short*)alloc((size_t)1024 * 1024 * 2);
    unsigned short* W3t = (unsigned short*)alloc((size_t)512 * 1024 * 2);
    unsigned short* W4t = (unsigned short*)alloc((size_t)128 * 512 * 2);
    unsigned short* Wit = (unsigned short*)alloc((size_t)512 * 128 * 2);
    unsigned short* Wg1t = (unsigned short*)alloc((size_t)512 * 512 * 2);
    unsigned short* Wg2t = (unsigned short*)alloc((size_t)512 * 512 * 2);
    unsigned short* Wot = (unsigned short*)alloc((size_t)128 * 512 * 2);
    int* cnt    = (int*)alloc((size_t)(N + 64) * 4);  // +bar tail (one memset)
    int* bar    = cnt + N;
    int* rowptr = (int*)alloc((size_t)(N + 1) * 4);
    int* cursor = (int*)alloc((size_t)N * 4);
    int* cols   = (int*)alloc((size_t)E * 4);
    int* bsums  = (int*)alloc(256);

    float* out_mask = (float*)d_out;                  // [N,80]
    float* out_feat = (float*)d_out + (size_t)N * 80; // [N,80]

    // ---- merged preprocessing: transposes + feat convert + edge count ----
    hipMemsetAsync(cnt, 0, (size_t)(N + 64) * 4, stream);   // zeroes cnt AND bar
    {
        PreDescs d;
        const float* Ws[8]  = {W1, W2, W3, W4, Wi, Wg1, Wg2, Wo};
        unsigned short* Ts[8] = {W1t, W2t, W3t, W4t, Wit, Wg1t, Wg2t, Wot};
        int Ks[8]  = {512, 1024, 1024, 512, 80, 512, 512, 512};
        int Ms[8]  = {1024, 1024, 512, 80, 512, 512, 512, 80};
        int Kps[8] = {512, 1024, 1024, 512, 128, 512, 512, 512};
        int Mps[8] = {1024, 1024, 512, 128, 512, 512, 512, 128};
        int st = 0;
        for (int i = 0; i < 8; ++i) {
            d.W[i] = Ws[i]; d.Wt[i] = Ts[i];
            d.K[i] = Ks[i]; d.M[i] = Ms[i]; d.Kp[i] = Kps[i];
            d.ntx[i] = Mps[i] / 32;
            d.start[i] = st;
            st += (Mps[i] / 32) * (Kps[i] / 32);
        }
        d.tEnd = st;
        d.cEnd = st + (N * 512) / 1024;
        d.eEnd = d.cEnd + (E + 255) / 256;
        d.feat = feat; d.featb = bufC; d.nFeat = N * 512;
        d.ei = ei; d.E = E; d.cnt = cnt;
        rg_preprocess<<<d.eEnd, 256, 0, stream>>>(d);
    }

    // ---- CSR: merged scan (1 coop kernel) + parallel scatter ----
    const int nb = (N + 1023) / 1024;   // 49 <= 64 (wave-scan limit)
    rg_scan_all<<<nb, 1024, 0, stream>>>(cnt, rowptr, cursor, bsums, bar, N, E, nb);
    rg_scatter_edges<<<(E + 255) / 256, 256, 0, stream>>>(ei, E, cursor, cols);

    const int rg8 = ((gN + 7) / 8) * 8;      // 392
    auto grid = [&](int MT) { return dim3(rg8 * MT); };

    // L1: h1 = relu(A0 @ W1 + b1)   [N,1024]
    rg_gemm<true, true, false, false, 8><<<grid(8), 256, 0, stream>>>(bufC, W1t, b1, nullptr, 1024, bufA, nullptr, N, 512, 1024, gN);

    // L2: h2 = relu(h1 @ W2 + b2)   [N,1024]  -- split into two row-halves so
    // the ~140us dispatch stops monopolizing rocprof top-5 (diagnostic).
    {
        const int halfTiles = (gN + 1) / 2;           // 196
        const int halfRows  = halfTiles * 128;        // 25088
        const int gNb       = gN - halfTiles;         // 195
        const int rg8a = ((halfTiles + 7) / 8) * 8;   // 200
        const int rg8b = ((gNb + 7) / 8) * 8;         // 200
        rg_gemm<true, true, false, false, 8><<<dim3(rg8a * 8), 256, 0, stream>>>(
            bufA, W2t, b2, nullptr, 1024, bufB, nullptr, halfRows, 1024, 1024, halfTiles);
        rg_gemm<true, true, false, false, 8><<<dim3(rg8b * 8), 256, 0, stream>>>(
            bufA + (size_t)halfRows * 1024, W2t, b2, nullptr, 1024,
            bufB + (size_t)halfRows * 1024, nullptr, N - halfRows, 1024, 1024, gNb);
    }

    // L3: h3 = relu(h2 @ W3 + b3)   [N,512]
    rg_gemm<true, true, false, false, 4><<<grid(4), 256, 0, stream>>>(bufB, W3t, b3, nullptr, 512, bufC, nullptr, N, 1024, 512, gN);
    // L4: pf = h3 @ W4 + b4  -> fp32 out_feat + bf16 padded [N,128]
    rg_gemm<false, true, true, false, 1><<<grid(1), 256, 0, stream>>>(bufC, W4t, b4, nullptr, 80, bufA, out_feat, N, 512, 128, gN);

    // 80-dim aggregation: s = pf + segsum(pf[src]) -> bufC[:, :128]
    rg_agg80<<<(N + 3) / 4, 256, 0, stream>>>(bufA, rowptr, cols, bufC, N);

    // L5: g = s @ Win + (1+deg)*bin  [N,512]   (agg moved before affine in_net)
    rg_gemm<false, true, false, true, 4><<<grid(4), 256, 0, stream>>>(bufC, Wit, bi, cnt, 512, bufA, nullptr, N, 128, 512, gN);
    // L6: r1 = relu(g @ Wg1 + bg1)  [N,512]
    rg_gemm<true, true, false, false, 4><<<grid(4), 256, 0, stream>>>(bufA, Wg1t, bg1, nullptr, 512, bufB, nullptr, N, 512, 512, gN);
    // L7: g2 = r1 @ Wg2 + bg2       [N,512]
    rg_gemm<false, true, false, false, 4><<<grid(4), 256, 0, stream>>>(bufB, Wg2t, bg2, nullptr, 512, bufC, nullptr, N, 512, 512, gN);
    // L8: mask = g2 @ Wout + bout -> fp32 out_mask
    rg_gemm<false, false, true, false, 1><<<grid(1), 256, 0, stream>>>(bufC, Wot, bo, nullptr, 80, nullptr, out_mask, N, 512, 128, gN);
}

// Round 8
// 782.898 us; speedup vs baseline: 1.0837x; 1.0837x over previous
//
#include <hip/hip_runtime.h>
#include <stdint.h>

// ---------------------------------------------------------------------------
// ResidueGraphModel: aanet_proj (512->1024->1024->512->80, ReLU) -> in_net
// (80->512) -> GIN sum-aggregation + MLP (512->512->512) -> out_net (512->80).
// bf16 MFMA GEMMs (fp32 accumulate), 128x128 tiles, BK=64, 16x16x32 MFMA.
// R8: revert R7's L2 row-split (cost ~30us: doubled ramp/tail, W2 L2 re-warm).
// Keep merged 49-block scan. NEW: edge scatter rides inside L1's dispatch as
// extra blocks (independent work: scatter needs only scan_all, L1 needs only
// preprocess) - memory/atomic-bound scatter overlaps compute-bound GEMM.
// GEMM core (frozen since R2/R4): XOR-swizzled LDS (0 bank conflicts),
// operand-swapped MFMA (packed 8B C stores), XCD-grouped decode, row-padded
// A buffers (no clamp), aggregation before in_net (80-dim gather).
// Outputs fp32: d_out = [peptide_mask (N*80) | peptide_feat (N*80)].
// ---------------------------------------------------------------------------

using bf16x8 = __attribute__((ext_vector_type(8))) short;
using f32x4  = __attribute__((ext_vector_type(4))) float;

__device__ inline unsigned short f2bf(float f) {
    union { float f; unsigned u; } v; v.f = f;
    unsigned u = v.u;
    u += 0x7FFFu + ((u >> 16) & 1u);   // RNE
    return (unsigned short)(u >> 16);
}
__device__ inline float bf2f(unsigned u16) {
    return __uint_as_float(u16 << 16);
}

// ------------- merged preprocessing ----------------------------------------
// Block ranges: [0, tEnd) -> weight transpose+convert (32x32 tiles, 256 thr)
//               [tEnd, cEnd) -> feat f32->bf16 convert (1024 elems/block)
//               [cEnd, eEnd) -> edge dst counting (256 edges/block)
struct PreDescs {
    const float* W[8]; unsigned short* Wt[8];
    int K[8], M[8], Kp[8], ntx[8], start[8];
    int tEnd, cEnd, eEnd;
    const float* feat; unsigned short* featb; int nFeat;
    const int* ei; int E; int* cnt;
};

__global__ __launch_bounds__(256) void rg_preprocess(PreDescs d) {
    int b = blockIdx.x;
    int tid = threadIdx.x;
    if (b < d.tEnd) {
        // transpose: W[K][M] f32 -> Wt[Mp][Kp] bf16 (pad with 0)
        __shared__ float t[32][33];
        int di = 0;
#pragma unroll
        for (int i = 1; i < 8; ++i) if (b >= d.start[i]) di = i;
        int local = b - d.start[di];
        int bx = local % d.ntx[di];
        int by = local / d.ntx[di];
        const float* W = d.W[di];
        unsigned short* Wt = d.Wt[di];
        int K = d.K[di], M = d.M[di], Kp = d.Kp[di];
        int mb = bx * 32, kb = by * 32;
        int tx = tid & 31, tg = tid >> 5;   // 8 rows per pass, 4 passes
#pragma unroll
        for (int p = 0; p < 4; ++p) {
            int r = tg + p * 8;             // tile row (k-dir)
            int k = kb + r, m = mb + tx;
            t[r][tx] = (k < K && m < M) ? W[(size_t)k * M + m] : 0.f;
        }
        __syncthreads();
#pragma unroll
        for (int p = 0; p < 4; ++p) {
            int r = tg + p * 8;             // tile row (m-dir)
            int mo = mb + r, ko = kb + tx;
            Wt[(size_t)mo * Kp + ko] = f2bf(t[tx][r]);
        }
    } else if (b < d.cEnd) {
        int i = ((b - d.tEnd) * 256 + tid) * 4;
        if (i + 3 < d.nFeat) {
            float4 v = *(const float4*)(d.feat + i);
            ushort4 o; o.x = f2bf(v.x); o.y = f2bf(v.y); o.z = f2bf(v.z); o.w = f2bf(v.w);
            *(ushort4*)(d.featb + i) = o;
        }
    } else {
        int e = (b - d.cEnd) * 256 + tid;
        if (e < d.E) atomicAdd(&d.cnt[d.ei[d.E + e]], 1);
    }
}

// ---------------- GEMM body: C[N,Mp] = act(A[N,Kp] @ Wt[Mp,Kp]^T + b) -------
// XOR swizzle: LDS chunk q (16B) of a tile row r holds global chunk
// (q&7)^(r&7); staging lane loads the matching global address, fragment
// reads apply the same XOR -> zero measured bank conflicts.
// Operand swap: weights as first MFMA operand -> acc regs hold 4 consecutive
// output columns -> 8B packed stores (32B/row per store instruction).
template <bool RELU, bool OUT_BF, bool OUT_F32, bool DEGB, int MT>
__device__ __forceinline__ void gemm_body(
    int bid,
    const unsigned short* __restrict__ A, const unsigned short* __restrict__ Bt,
    const float* __restrict__ bias, const int* __restrict__ deg, int Mvalid,
    unsigned short* __restrict__ outB, float* __restrict__ outF,
    int Nrows, int Kp, int Mp, int gN)
{
    __shared__ __align__(16) unsigned short As[128 * 64];
    __shared__ __align__(16) unsigned short Bs[128 * 64];

    // XCD-grouped decode: a row strip's MT col-blocks share (bid&7), 8 apart
    // in issue order -> A strip stays hot in L2/L3 across column passes.
    int xcd = bid & 7;
    int slot = bid >> 3;
    int c = slot % MT;
    int rsub = slot / MT;
    int rt = rsub * 8 + xcd;
    if (rt >= gN) return;
    const int rowBase = rt * 128;
    const int nBase   = c * 128;

    const int tid  = threadIdx.x;
    const int lane = tid & 63;
    const int w    = tid >> 6;
    const int wm   = w & 1, wn = w >> 1;

    f32x4 acc[4][4];
#pragma unroll
    for (int i = 0; i < 4; ++i)
#pragma unroll
        for (int j = 0; j < 4; ++j) acc[i][j] = (f32x4){0.f, 0.f, 0.f, 0.f};

    const int nkt = Kp >> 6;
    for (int kt = 0; kt < nkt; ++kt) {
        __syncthreads();
        const int k0 = kt * 64;
#pragma unroll
        for (int i = 0; i < 4; ++i) {
            int q   = i * 256 + tid;       // LDS 16B-chunk slot
            int r   = q >> 3;
            int cbg = (q & 7) ^ (r & 7);   // global chunk staged into slot q
            const unsigned short* gp = A + (size_t)(rowBase + r) * Kp + k0 + cbg * 8;
            __builtin_amdgcn_global_load_lds(
                (const __attribute__((address_space(1))) void*)gp,
                (__attribute__((address_space(3))) void*)(&As[q * 8]), 16, 0, 0);
        }
#pragma unroll
        for (int i = 0; i < 4; ++i) {
            int q   = i * 256 + tid;
            int r   = q >> 3;
            int cbg = (q & 7) ^ (r & 7);
            const unsigned short* gp = Bt + (size_t)(nBase + r) * Kp + k0 + cbg * 8;
            __builtin_amdgcn_global_load_lds(
                (const __attribute__((address_space(1))) void*)gp,
                (__attribute__((address_space(3))) void*)(&Bs[q * 8]), 16, 0, 0);
        }
        __syncthreads();
#pragma unroll
        for (int kk = 0; kk < 2; ++kk) {
            bf16x8 a[4], b[4];
            const int cb = kk * 4 + (lane >> 4);
#pragma unroll
            for (int i = 0; i < 4; ++i) {
                int r = wm * 64 + i * 16 + (lane & 15);
                a[i] = *(const bf16x8*)&As[(r * 8 + (cb ^ (r & 7))) * 8];
            }
#pragma unroll
            for (int j = 0; j < 4; ++j) {
                int r = wn * 64 + j * 16 + (lane & 15);
                b[j] = *(const bf16x8*)&Bs[(r * 8 + (cb ^ (r & 7))) * 8];
            }
#pragma unroll
            for (int i = 0; i < 4; ++i)
#pragma unroll
                for (int j = 0; j < 4; ++j)
                    // swapped: weights first -> D cols from regs, rows from lane
                    acc[i][j] = __builtin_amdgcn_mfma_f32_16x16x32_bf16(b[j], a[i], acc[i][j], 0, 0, 0);
        }
    }

    // epilogue (swapped layout): row = ...+(lane&15); col = ...+quad*4+reg
    const int quad = lane >> 4;
#pragma unroll
    for (int i = 0; i < 4; ++i) {
        int row = rowBase + wm * 64 + i * 16 + (lane & 15);
        if (row >= Nrows) continue;
        float sc = 1.f;
        if (DEGB) sc = 1.f + (float)deg[row];
#pragma unroll
        for (int j = 0; j < 4; ++j) {
            int colb = nBase + wn * 64 + j * 16 + quad * 4;
            float4 bv = (colb < Mvalid) ? *(const float4*)(bias + colb)
                                        : (float4){0.f, 0.f, 0.f, 0.f};
            float v0 = acc[i][j][0] + sc * bv.x;
            float v1 = acc[i][j][1] + sc * bv.y;
            float v2 = acc[i][j][2] + sc * bv.z;
            float v3 = acc[i][j][3] + sc * bv.w;
            if (RELU) {
                v0 = v0 > 0.f ? v0 : 0.f; v1 = v1 > 0.f ? v1 : 0.f;
                v2 = v2 > 0.f ? v2 : 0.f; v3 = v3 > 0.f ? v3 : 0.f;
            }
            if (OUT_BF) {
                ushort4 o; o.x = f2bf(v0); o.y = f2bf(v1); o.z = f2bf(v2); o.w = f2bf(v3);
                *(ushort4*)(outB + (size_t)row * Mp + colb) = o;
            }
            if (OUT_F32) {
                if (colb < Mvalid)
                    *(float4*)(outF + (size_t)row * Mvalid + colb) = (float4){v0, v1, v2, v3};
            }
        }
    }
}

template <bool RELU, bool OUT_BF, bool OUT_F32, bool DEGB, int MT>
__global__ __launch_bounds__(256) void rg_gemm(
    const unsigned short* __restrict__ A, const unsigned short* __restrict__ Bt,
    const float* __restrict__ bias, const int* __restrict__ deg, int Mvalid,
    unsigned short* __restrict__ outB, float* __restrict__ outF,
    int Nrows, int Kp, int Mp, int gN)
{
    gemm_body<RELU, OUT_BF, OUT_F32, DEGB, MT>(blockIdx.x, A, Bt, bias, deg,
                                               Mvalid, outB, outF, Nrows, Kp, Mp, gN);
}

// L1 GEMM + edge scatter in one dispatch: blocks [0, gemmBlocks) do the GEMM,
// the rest scatter edges into CSR (independent work, disjoint memory; scatter
// backfills CUs as GEMM blocks retire -> hidden behind compute).
__global__ __launch_bounds__(256) void rg_gemm_l1_scatter(
    const unsigned short* __restrict__ A, const unsigned short* __restrict__ Bt,
    const float* __restrict__ bias, int Mvalid,
    unsigned short* __restrict__ outB, int Nrows, int Kp, int Mp, int gN,
    int gemmBlocks, const int* __restrict__ ei, int E,
    int* __restrict__ cursor, int* __restrict__ cols)
{
    int bid = blockIdx.x;
    if (bid < gemmBlocks) {
        gemm_body<true, true, false, false, 8>(bid, A, Bt, bias, nullptr,
                                               Mvalid, outB, nullptr, Nrows, Kp, Mp, gN);
    } else {
        int e = (bid - gemmBlocks) * 256 + threadIdx.x;
        if (e < E) {
            int d = ei[E + e];
            int p = atomicAdd(&cursor[d], 1);
            cols[p] = ei[e];
        }
    }
}

// ---------------- merged scan (3 dispatches -> 1) ---------------------------
// 49 blocks x 1024 threads, co-resident (grid << 256 CUs). Stages were
// already 49-block / 1-wave shaped -> merge loses no parallelism.
__device__ __forceinline__ void rg_gridbar(int* bar, int nb, int phase) {
    __syncthreads();
    if (threadIdx.x == 0) {
        __threadfence();
        atomicAdd(bar, 1);
        int target = phase * nb;
        while (__hip_atomic_load(bar, __ATOMIC_RELAXED, __HIP_MEMORY_SCOPE_AGENT) < target) {}
        __threadfence();
    }
    __syncthreads();
}

__global__ __launch_bounds__(1024) void rg_scan_all(
    const int* __restrict__ cnt, int* __restrict__ rowptr, int* __restrict__ cursor,
    int* __restrict__ bsums, int* bar, int Nn, int E, int nb)
{
    __shared__ int sd[1024];
    const int tid = threadIdx.x;
    const int bid = blockIdx.x;
    const int i   = bid * 1024 + tid;

    // stage 1: block-local inclusive scan of this block's 1024-chunk
    int v = (i < Nn) ? cnt[i] : 0;
    sd[tid] = v;
    __syncthreads();
    for (int off = 1; off < 1024; off <<= 1) {
        int t = (tid >= off) ? sd[tid - off] : 0;
        __syncthreads();
        sd[tid] += t;
        __syncthreads();
    }
    if (tid == 1023) bsums[bid] = sd[1023];
    rg_gridbar(bar, nb, 1);

    // stage 2: exclusive wave-scan of block sums (block 0, nb <= 64)
    if (bid == 0 && tid < 64) {
        int bv = (tid < nb) ? bsums[tid] : 0;
        int incl = bv;
#pragma unroll
        for (int off = 1; off < 64; off <<= 1) {
            int t = __shfl_up(incl, off, 64);
            if (tid >= off) incl += t;
        }
        if (tid < nb) bsums[tid] = incl - bv;   // exclusive
    }
    rg_gridbar(bar, nb, 2);

    // stage 3: write rowptr + cursor (sd persisted across barriers)
    if (i < Nn) {
        int ex = sd[tid] - v + bsums[bid];
        rowptr[i] = ex; cursor[i] = ex;
    }
    if (i == 0) rowptr[Nn] = E;
}

// ---------------- 80-dim aggregation: s[i] = pf[i] + sum_{src->i} pf[src] --
// pf is [Npad,128] bf16. One wave per node, 1 uint (2 cols) per lane.
// Edge loop unrolled x8: 8 independent outstanding gathers per iteration.
__global__ __launch_bounds__(256) void rg_agg80(
    const unsigned short* __restrict__ pf, const int* __restrict__ rowptr,
    const int* __restrict__ cols, unsigned short* __restrict__ s, int Nn)
{
    int node = blockIdx.x * 4 + (threadIdx.x >> 6);
    if (node >= Nn) return;
    int lane = threadIdx.x & 63;
    const unsigned* xp = (const unsigned*)pf;   // 64 uints per row
    size_t off = (size_t)node * 64 + lane;
    unsigned u = xp[off];
    float a0 = bf2f(u & 0xffffu), a1 = bf2f(u >> 16);
    int beg = rowptr[node], end = rowptr[node + 1];
    int e = beg;
    for (; e + 8 <= end; e += 8) {
        unsigned v[8];
#pragma unroll
        for (int t = 0; t < 8; ++t) v[t] = xp[(size_t)cols[e + t] * 64 + lane];
#pragma unroll
        for (int t = 0; t < 8; ++t) { a0 += bf2f(v[t] & 0xffffu); a1 += bf2f(v[t] >> 16); }
    }
    for (; e < end; ++e) {
        unsigned v = xp[(size_t)cols[e] * 64 + lane];
        a0 += bf2f(v & 0xffffu); a1 += bf2f(v >> 16);
    }
    unsigned o = (unsigned)f2bf(a0) | ((unsigned)f2bf(a1) << 16);
    ((unsigned*)s)[off] = o;
}

// ---------------------------------------------------------------------------
extern "C" void kernel_launch(void* const* d_in, const int* in_sizes, int n_in,
                              void* d_out, int out_size, void* d_ws, size_t ws_size,
                              hipStream_t stream)
{
    const float* feat = (const float*)d_in[0];
    const int*   ei   = (const int*)d_in[1];
    const float* W1 = (const float*)d_in[2];  const float* b1 = (const float*)d_in[3];
    const float* W2 = (const float*)d_in[4];  const float* b2 = (const float*)d_in[5];
    const float* W3 = (const float*)d_in[6];  const float* b3 = (const float*)d_in[7];
    const float* W4 = (const float*)d_in[8];  const float* b4 = (const float*)d_in[9];
    const float* Wi = (const float*)d_in[10]; const float* bi = (const float*)d_in[11];
    const float* Wg1 = (const float*)d_in[12]; const float* bg1 = (const float*)d_in[13];
    const float* Wg2 = (const float*)d_in[14]; const float* bg2 = (const float*)d_in[15];
    const float* Wo = (const float*)d_in[16]; const float* bo = (const float*)d_in[17];

    const int N = in_sizes[0] / 512;   // 50000
    const int E = in_sizes[1] / 2;     // 800000
    const int gN = (N + 127) / 128;    // 391
    const int Npad = gN * 128;         // 50048: GEMM A-loads never clamp

    char* ws = (char*)d_ws;
    size_t o = 0;
    auto alloc = [&](size_t bytes) { char* p = ws + o; o += (bytes + 255) & ~(size_t)255; return p; };
    unsigned short* bufA = (unsigned short*)alloc((size_t)Npad * 1024 * 2); // h1 / pf / g
    unsigned short* bufB = (unsigned short*)alloc((size_t)Npad * 1024 * 2); // h2 / r1
    unsigned short* bufC = (unsigned short*)alloc((size_t)Npad * 512 * 2);  // A0 / h3 / s / g2
    unsigned short* W1t = (unsigned short*)alloc((size_t)1024 * 512 * 2);
    unsigned short* W2t = (unsigned short*)alloc((size_t)1024 * 1024 * 2);
    unsigned short* W3t = (unsigned short*)alloc((size_t)512 * 1024 * 2);
    unsigned short* W4t = (unsigned short*)alloc((size_t)128 * 512 * 2);
    unsigned short* Wit = (unsigned short*)alloc((size_t)512 * 128 * 2);
    unsigned short* Wg1t = (unsigned short*)alloc((size_t)512 * 512 * 2);
    unsigned short* Wg2t = (unsigned short*)alloc((size_t)512 * 512 * 2);
    unsigned short* Wot = (unsigned short*)alloc((size_t)128 * 512 * 2);
    int* cnt    = (int*)alloc((size_t)(N + 64) * 4);  // +bar tail (one memset)
    int* bar    = cnt + N;
    int* rowptr = (int*)alloc((size_t)(N + 1) * 4);
    int* cursor = (int*)alloc((size_t)N * 4);
    int* cols   = (int*)alloc((size_t)E * 4);
    int* bsums  = (int*)alloc(256);

    float* out_mask = (float*)d_out;                  // [N,80]
    float* out_feat = (float*)d_out + (size_t)N * 80; // [N,80]

    // ---- merged preprocessing: transposes + feat convert + edge count ----
    hipMemsetAsync(cnt, 0, (size_t)(N + 64) * 4, stream);   // zeroes cnt AND bar
    {
        PreDescs d;
        const float* Ws[8]  = {W1, W2, W3, W4, Wi, Wg1, Wg2, Wo};
        unsigned short* Ts[8] = {W1t, W2t, W3t, W4t, Wit, Wg1t, Wg2t, Wot};
        int Ks[8]  = {512, 1024, 1024, 512, 80, 512, 512, 512};
        int Ms[8]  = {1024, 1024, 512, 80, 512, 512, 512, 80};
        int Kps[8] = {512, 1024, 1024, 512, 128, 512, 512, 512};
        int Mps[8] = {1024, 1024, 512, 128, 512, 512, 512, 128};
        int st = 0;
        for (int i = 0; i < 8; ++i) {
            d.W[i] = Ws[i]; d.Wt[i] = Ts[i];
            d.K[i] = Ks[i]; d.M[i] = Ms[i]; d.Kp[i] = Kps[i];
            d.ntx[i] = Mps[i] / 32;
            d.start[i] = st;
            st += (Mps[i] / 32) * (Kps[i] / 32);
        }
        d.tEnd = st;
        d.cEnd = st + (N * 512) / 1024;
        d.eEnd = d.cEnd + (E + 255) / 256;
        d.feat = feat; d.featb = bufC; d.nFeat = N * 512;
        d.ei = ei; d.E = E; d.cnt = cnt;
        rg_preprocess<<<d.eEnd, 256, 0, stream>>>(d);
    }

    // ---- CSR scan: one cooperative kernel (49 blocks) ----
    const int nb = (N + 1023) / 1024;   // 49 <= 64 (wave-scan limit)
    rg_scan_all<<<nb, 1024, 0, stream>>>(cnt, rowptr, cursor, bsums, bar, N, E, nb);

    const int rg8 = ((gN + 7) / 8) * 8;      // 392
    auto grid = [&](int MT) { return dim3(rg8 * MT); };

    // L1: h1 = relu(A0 @ W1 + b1)   [N,1024]  + edge scatter riding along
    {
        const int gemmBlocks = rg8 * 8;             // 3136
        const int scatBlocks = (E + 255) / 256;     // 3125
        rg_gemm_l1_scatter<<<dim3(gemmBlocks + scatBlocks), 256, 0, stream>>>(
            bufC, W1t, b1, 1024, bufA, N, 512, 1024, gN,
            gemmBlocks, ei, E, cursor, cols);
    }

    // L2: h2 = relu(h1 @ W2 + b2)   [N,1024]
    rg_gemm<true, true, false, false, 8><<<grid(8), 256, 0, stream>>>(bufA, W2t, b2, nullptr, 1024, bufB, nullptr, N, 1024, 1024, gN);
    // L3: h3 = relu(h2 @ W3 + b3)   [N,512]
    rg_gemm<true, true, false, false, 4><<<grid(4), 256, 0, stream>>>(bufB, W3t, b3, nullptr, 512, bufC, nullptr, N, 1024, 512, gN);
    // L4: pf = h3 @ W4 + b4  -> fp32 out_feat + bf16 padded [N,128]
    rg_gemm<false, true, true, false, 1><<<grid(1), 256, 0, stream>>>(bufC, W4t, b4, nullptr, 80, bufA, out_feat, N, 512, 128, gN);

    // 80-dim aggregation: s = pf + segsum(pf[src]) -> bufC[:, :128]
    rg_agg80<<<(N + 3) / 4, 256, 0, stream>>>(bufA, rowptr, cols, bufC, N);

    // L5: g = s @ Win + (1+deg)*bin  [N,512]   (agg moved before affine in_net)
    rg_gemm<false, true, false, true, 4><<<grid(4), 256, 0, stream>>>(bufC, Wit, bi, cnt, 512, bufA, nullptr, N, 128, 512, gN);
    // L6: r1 = relu(g @ Wg1 + bg1)  [N,512]
    rg_gemm<true, true, false, false, 4><<<grid(4), 256, 0, stream>>>(bufA, Wg1t, bg1, nullptr, 512, bufB, nullptr, N, 512, 512, gN);
    // L7: g2 = r1 @ Wg2 + bg2       [N,512]
    rg_gemm<false, true, false, false, 4><<<grid(4), 256, 0, stream>>>(bufB, Wg2t, bg2, nullptr, 512, bufC, nullptr, N, 512, 512, gN);
    // L8: mask = g2 @ Wout + bout -> fp32 out_mask
    rg_gemm<false, false, true, false, 1><<<grid(1), 256, 0, stream>>>(bufC, Wot, bo, nullptr, 80, nullptr, out_mask, N, 512, 128, gN);
}